// Round 2
// baseline (40450.998 us; speedup 1.0000x reference)
//
#include <hip/hip_runtime.h>
#include <cmath>

// Problem constants (B=2, C=64, H=W=256)
static constexpr int Bn   = 2;
static constexpr int Cn   = 64;
static constexpr int Hn   = 256;
static constexpr int Wn   = 256;
static constexpr int HW   = Hn * Wn;          // 65536
static constexpr int CHW  = Cn * HW;          // 4194304
static constexpr int NCHW = Bn * CHW;         // 8388608
static constexpr int NPIX = Bn * HW;          // 131072
static constexpr float EPSv = 1e-5f;
static constexpr float INV_N = 1.0f / 131072.0f;   // BN count = B*H*W

// ---------------------------------------------------------------------------
// Weight transpose: in[nb][oc][ic][k] -> out[nb][(ic*K+k)*OC + oc]
// ---------------------------------------------------------------------------
__global__ void transpose_w_kernel(const float* __restrict__ in, float* __restrict__ out,
                                   int NB, int OC, int IC, int K) {
  int total = NB * OC * IC * K;
  for (int i = blockIdx.x * blockDim.x + threadIdx.x; i < total; i += gridDim.x * blockDim.x) {
    int k  = i % K;
    int t  = i / K;
    int ic = t % IC; t /= IC;
    int oc = t % OC;
    int nb = t / OC;
    out[(((size_t)nb * IC + ic) * K + k) * OC + oc] = in[i];
  }
}

// ---------------------------------------------------------------------------
// Prep: error = conv0(concat(Slope,Dist,Level)) (1x1), masked; x0 = ...
// ---------------------------------------------------------------------------
__global__ void prep_kernel(const float* __restrict__ LowDEM, const float* __restrict__ Point_Ele,
                            const float* __restrict__ Slope, const float* __restrict__ Distance,
                            const float* __restrict__ Level, const float* __restrict__ w0,
                            const float* __restrict__ b0, float* __restrict__ x0) {
  int i = blockIdx.x * blockDim.x + threadIdx.x;
  if (i >= NPIX) return;
  float lv  = Level[i];
  float err = w0[0] * Slope[i] + w0[1] * Distance[i] + w0[2] * lv + b0[0];
  float lm  = (lv != 0.0f) ? 1.0f : 0.0f;
  x0[i] = LowDEM[i] * (1.0f - lm) + Point_Ele[i] + err * lm;
}

// ---------------------------------------------------------------------------
// conv1: 9x9, 1 -> 64 channels, pad 4.  wT layout: [tap(81)][oc(64)]
// ---------------------------------------------------------------------------
__global__ __launch_bounds__(256, 2)
void conv9x9_kernel(const float* __restrict__ in, const float* __restrict__ wT,
                    const float* __restrict__ bias, float* __restrict__ out) {
  const int tx = threadIdx.x & 15, ty = threadIdx.x >> 4;
  const int w0 = blockIdx.x * 16, h0 = blockIdx.y * 16, b = blockIdx.z;
  __shared__ float lds[24 * 24];
  for (int idx = threadIdx.x; idx < 576; idx += 256) {
    int yy = idx / 24, xx = idx - yy * 24;
    int gy = h0 + yy - 4, gx = w0 + xx - 4;
    float v = 0.0f;
    if ((unsigned)gy < 256u && (unsigned)gx < 256u) v = in[b * HW + gy * 256 + gx];
    lds[idx] = v;
  }
  __syncthreads();
  float acc[64];
#pragma unroll
  for (int o = 0; o < 64; o++) acc[o] = 0.0f;
#pragma unroll 1
  for (int i = 0; i < 9; i++) {
#pragma unroll
    for (int j = 0; j < 9; j++) {
      float v = lds[(ty + i) * 24 + tx + j];
      const float* wp = wT + (i * 9 + j) * 64;   // uniform address -> s_load
#pragma unroll
      for (int o = 0; o < 64; o++) acc[o] = fmaf(v, wp[o], acc[o]);
    }
  }
  const int p = (h0 + ty) * 256 + (w0 + tx);
  float* op = out + (size_t)b * CHW + p;
#pragma unroll
  for (int o = 0; o < 64; o++) op[o * HW] = acc[o] + bias[o];
}

// ---------------------------------------------------------------------------
// conv3x3: 64 -> OC channels, pad 1.
// wT layout: [(ic*9+tap)*OC + oc]  (OC contiguous -> uniform scalar loads)
// BNIN==1: input is raw conv output t; apply r = relu(t*scale+shift) on the
//          LDS staging load (zero padding applied AFTER the transform, as ref).
// STATS==1: fused BN statistics for the OUTPUT: per-wave shuffle reduction of
//           sum/sumsq per oc, one atomicAdd pair per wave per oc.
// ---------------------------------------------------------------------------
template <int OC, int BNIN, int STATS>
__global__ __launch_bounds__(256, 2)
void conv3x3_kernel(const float* __restrict__ in, const float* __restrict__ wT,
                    const float* __restrict__ bias, const float* __restrict__ stats_in,
                    const float* __restrict__ g, const float* __restrict__ be,
                    float* __restrict__ stats_out, float* __restrict__ out) {
  const int tx = threadIdx.x & 15, ty = threadIdx.x >> 4;
  const int lane = threadIdx.x & 63;
  const int w0 = blockIdx.x * 16, h0 = blockIdx.y * 16, b = blockIdx.z;
  __shared__ float lds[16][324];     // 16 channels x 18x18 tile
  __shared__ float s_sc[64], s_sh[64];
  if (BNIN) {
    if (threadIdx.x < 64) {
      int c = threadIdx.x;
      float m   = stats_in[c] * INV_N;
      float var = stats_in[64 + c] * INV_N - m * m;
      float s   = g[c] * rsqrtf(var + EPSv);
      s_sc[c] = s;
      s_sh[c] = be[c] - m * s;
    }
  }
  float acc[OC];
#pragma unroll
  for (int o = 0; o < OC; o++) acc[o] = 0.0f;
  const float* inb = in + (size_t)b * CHW;
  for (int cb = 0; cb < 64; cb += 16) {
    __syncthreads();
    for (int idx = threadIdx.x; idx < 16 * 324; idx += 256) {
      int c  = idx / 324;
      int r  = idx - c * 324;
      int yy = r / 18, xx = r - yy * 18;
      int gy = h0 + yy - 1, gx = w0 + xx - 1;
      float v = 0.0f;
      if ((unsigned)gy < 256u && (unsigned)gx < 256u) {
        v = inb[(cb + c) * HW + gy * 256 + gx];
        if (BNIN) v = fmaxf(fmaf(v, s_sc[cb + c], s_sh[cb + c]), 0.0f);
      }
      lds[c][r] = v;
    }
    __syncthreads();
#pragma unroll 1
    for (int c = 0; c < 16; c++) {
      const float* wp = wT + ((cb + c) * 9) * OC;   // uniform -> s_load
#pragma unroll
      for (int t = 0; t < 9; t++) {
        float v = lds[c][(ty + t / 3) * 18 + tx + t % 3];
#pragma unroll
        for (int o = 0; o < OC; o++) acc[o] = fmaf(v, wp[t * OC + o], acc[o]);
      }
    }
  }
  const int p = (h0 + ty) * 256 + (w0 + tx);
  float* op = out + (size_t)b * OC * HW + p;
#pragma unroll
  for (int o = 0; o < OC; o++) {
    float v = acc[o];
    if (bias) v += bias[o];
    op[o * HW] = v;
    if (STATS) {
      float s = v, s2 = v * v;
#pragma unroll
      for (int off = 32; off > 0; off >>= 1) {
        s  += __shfl_down(s, off, 64);
        s2 += __shfl_down(s2, off, 64);
      }
      if (lane == 0) {
        atomicAdd(&stats_out[o],      s);
        atomicAdd(&stats_out[64 + o], s2);
      }
    }
  }
}

// ---------------------------------------------------------------------------
// y = BN(t)*g+be + skip   (vectorized float4, scale/shift precomputed in LDS)
// ---------------------------------------------------------------------------
__global__ void bn_apply_add_kernel(const float* __restrict__ t, const float* __restrict__ stats,
                                    const float* __restrict__ g, const float* __restrict__ be,
                                    const float* __restrict__ skip, float* __restrict__ out) {
  __shared__ float s_sc[64], s_sh[64];
  if (threadIdx.x < 64) {
    int c = threadIdx.x;
    float m   = stats[c] * INV_N;
    float var = stats[64 + c] * INV_N - m * m;
    float s   = g[c] * rsqrtf(var + EPSv);
    s_sc[c] = s;
    s_sh[c] = be[c] - m * s;
  }
  __syncthreads();
  const float4* t4 = (const float4*)t;
  const float4* k4 = (const float4*)skip;
  float4* o4 = (float4*)out;
  const int n4 = NCHW / 4;
  for (int i = blockIdx.x * blockDim.x + threadIdx.x; i < n4; i += gridDim.x * blockDim.x) {
    int c = (i >> 14) & 63;     // HW/4 = 16384 vec4 per channel
    float s = s_sc[c], h = s_sh[c];
    float4 v = t4[i], kk = k4[i], r;
    r.x = fmaf(v.x, s, h) + kk.x;
    r.y = fmaf(v.y, s, h) + kk.y;
    r.z = fmaf(v.z, s, h) + kk.z;
    r.w = fmaf(v.w, s, h) + kk.w;
    o4[i] = r;
  }
}

// ---------------------------------------------------------------------------
// Deformable conv main, chunked for cache locality:
//   for cb (16-ch chunks) { for k (9 taps) { recompute coeffs; 16x gather+FMA } }
// Working set per chunk ~23 KB -> L1-resident across the 9 taps (the R0
// version swept all 64 planes per tap -> 9x HBM re-fetch, 458 MB/dispatch).
// FINAL==1 (OC==1): fuse dc4 bias + conv4 1x1, write d_out (B,1,H,W).
// ---------------------------------------------------------------------------
template <int OC, int FINAL>
__global__ __launch_bounds__(256, 2)
void dcn_kernel(const float* __restrict__ x, const float* __restrict__ om,
                const float* __restrict__ wT, const float* __restrict__ bias,
                const float* __restrict__ c4w, const float* __restrict__ c4b,
                float* __restrict__ out) {
  const int tx = threadIdx.x & 15, ty = threadIdx.x >> 4;
  const int w0 = blockIdx.x * 16, h0 = blockIdx.y * 16, b = blockIdx.z;
  const int h = h0 + ty, w = w0 + tx;
  const int p = h * 256 + w;
  float acc[OC];
#pragma unroll
  for (int o = 0; o < OC; o++) acc[o] = 0.0f;
  const float* xb  = x + (size_t)b * CHW;
  const float* omb = om + (size_t)b * 27 * HW + p;
#pragma unroll 1
  for (int cb = 0; cb < 64; cb += 16) {
#pragma unroll 1
    for (int k = 0; k < 9; k++) {
      float dyv = omb[k * HW];
      float dxv = omb[(9 + k) * HW];
      float mo  = omb[(18 + k) * HW];
      float mk  = 1.0f / (1.0f + __expf(-mo));
      float ys = (float)(h + k / 3 - 1) + dyv;
      float xs = (float)(w + k % 3 - 1) + dxv;
      float y0f = floorf(ys), x0f = floorf(xs);
      float wy = ys - y0f, wx = xs - x0f;
      int y0 = (int)y0f, x0i = (int)x0f;
      int y1 = y0 + 1, x1 = x0i + 1;
      float vy0 = ((unsigned)y0  < 256u) ? 1.0f : 0.0f;
      float vy1 = ((unsigned)y1  < 256u) ? 1.0f : 0.0f;
      float vx0 = ((unsigned)x0i < 256u) ? 1.0f : 0.0f;
      float vx1 = ((unsigned)x1  < 256u) ? 1.0f : 0.0f;
      int cy0 = min(max(y0, 0), 255), cy1 = min(max(y1, 0), 255);
      int cx0 = min(max(x0i, 0), 255), cx1 = min(max(x1, 0), 255);
      int i00 = cy0 * 256 + cx0, i01 = cy0 * 256 + cx1;
      int i10 = cy1 * 256 + cx0, i11 = cy1 * 256 + cx1;
      float W00 = (1.0f - wy) * (1.0f - wx) * mk * vy0 * vx0;
      float W01 = (1.0f - wy) * wx * mk * vy0 * vx1;
      float W10 = wy * (1.0f - wx) * mk * vy1 * vx0;
      float W11 = wy * wx * mk * vy1 * vx1;
#pragma unroll 2
      for (int c = 0; c < 16; c++) {
        const float* xc = xb + (cb + c) * HW;
        float sv = W00 * xc[i00] + W01 * xc[i01] + W10 * xc[i10] + W11 * xc[i11];
        const float* wp = wT + ((cb + c) * 9 + k) * OC;   // uniform -> s_load
#pragma unroll
        for (int o = 0; o < OC; o++) acc[o] = fmaf(sv, wp[o], acc[o]);
      }
    }
  }
  if (FINAL) {
    float v = acc[0] + bias[0];
    out[(size_t)b * HW + p] = c4w[0] * v + c4b[0];
  } else {
    float* op = out + (size_t)b * OC * HW + p;
#pragma unroll
    for (int o = 0; o < OC; o++) op[o * HW] = fmaxf(acc[o] + bias[o], 0.0f);
  }
}

// ---------------------------------------------------------------------------
extern "C" void kernel_launch(void* const* d_in, const int* in_sizes, int n_in,
                              void* d_out, int out_size, void* d_ws, size_t ws_size,
                              hipStream_t stream) {
  const float* LowDEM    = (const float*)d_in[0];
  const float* Point_Ele = (const float*)d_in[1];
  const float* Slope     = (const float*)d_in[2];
  const float* Distance  = (const float*)d_in[3];
  const float* Level     = (const float*)d_in[4];
  const float* conv0_w   = (const float*)d_in[5];
  const float* conv0_b   = (const float*)d_in[6];
  const float* conv1_w   = (const float*)d_in[7];
  const float* conv1_b   = (const float*)d_in[8];
  const float* rb_w1     = (const float*)d_in[9];
  const float* rb_g1     = (const float*)d_in[11];
  const float* rb_be1    = (const float*)d_in[12];
  const float* rb_w2     = (const float*)d_in[13];
  const float* rb_g2     = (const float*)d_in[15];
  const float* rb_be2    = (const float*)d_in[16];
  const float* conv2_w   = (const float*)d_in[17];
  const float* bn2_g     = (const float*)d_in[19];
  const float* bn2_be    = (const float*)d_in[20];
  const float* dc2_w     = (const float*)d_in[21];
  const float* dc2_b     = (const float*)d_in[22];
  const float* dc2_ow    = (const float*)d_in[23];
  const float* dc2_ob    = (const float*)d_in[24];
  const float* dc3_w     = (const float*)d_in[25];
  const float* dc3_b     = (const float*)d_in[26];
  const float* dc3_ow    = (const float*)d_in[27];
  const float* dc3_ob    = (const float*)d_in[28];
  const float* dc4_w     = (const float*)d_in[29];
  const float* dc4_b     = (const float*)d_in[30];
  const float* dc4_ow    = (const float*)d_in[31];
  const float* dc4_ob    = (const float*)d_in[32];
  const float* conv4_w   = (const float*)d_in[33];
  const float* conv4_b   = (const float*)d_in[34];

  float* Wp   = (float*)d_ws;
  float* bufX = Wp;                       // 8388608 floats each
  float* bufY = bufX + NCHW;
  float* bufT = bufY + NCHW;
  float* bufT2= bufT + NCHW;
  float* x0   = bufT2 + NCHW;             // 131072
  float* T1   = x0 + NPIX;                // 81*64   = 5184
  float* Trb1 = T1 + 5184;                // 16*576*64 = 589824
  float* Trb2 = Trb1 + 589824;
  float* Tc2  = Trb2 + 589824;            // 36864
  float* Tow2 = Tc2 + 36864;              // 576*27 = 15552
  float* Tow3 = Tow2 + 15552;
  float* Tow4 = Tow3 + 15552;
  float* Tdw2 = Tow4 + 15552;             // 36864
  float* Tdw3 = Tdw2 + 36864;
  float* stats= Tdw3 + 36864;             // 33 slots * 128 floats

  hipMemsetAsync(stats, 0, 33 * 128 * sizeof(float), stream);

  transpose_w_kernel<<<256, 256, 0, stream>>>(rb_w1,   Trb1, 16, 64, 64, 9);
  transpose_w_kernel<<<256, 256, 0, stream>>>(rb_w2,   Trb2, 16, 64, 64, 9);
  transpose_w_kernel<<<32,  256, 0, stream>>>(conv1_w, T1,    1, 64,  1, 81);
  transpose_w_kernel<<<64,  256, 0, stream>>>(conv2_w, Tc2,   1, 64, 64, 9);
  transpose_w_kernel<<<32,  256, 0, stream>>>(dc2_ow,  Tow2,  1, 27, 64, 9);
  transpose_w_kernel<<<32,  256, 0, stream>>>(dc3_ow,  Tow3,  1, 27, 64, 9);
  transpose_w_kernel<<<32,  256, 0, stream>>>(dc4_ow,  Tow4,  1, 27, 64, 9);
  transpose_w_kernel<<<64,  256, 0, stream>>>(dc2_w,   Tdw2,  1, 64, 64, 9);
  transpose_w_kernel<<<64,  256, 0, stream>>>(dc3_w,   Tdw3,  1, 64, 64, 9);

  prep_kernel<<<(NPIX + 255) / 256, 256, 0, stream>>>(LowDEM, Point_Ele, Slope, Distance,
                                                      Level, conv0_w, conv0_b, x0);

  dim3 grid16(16, 16, 2);

  conv9x9_kernel<<<grid16, 256, 0, stream>>>(x0, T1, conv1_b, bufX);   // X in bufX

  for (int i = 0; i < 16; i++) {
    const float* src = (i == 0) ? bufX : bufY;
    // t1 = conv(y, w1)  (bias dropped: cancelled by BN); stats fused in epilogue
    conv3x3_kernel<64, 0, 1><<<grid16, 256, 0, stream>>>(src, Trb1 + (size_t)i * 36864,
                                                         nullptr, nullptr, nullptr, nullptr,
                                                         stats + (2 * i) * 128, bufT);
    // t2 = conv(relu(bn(t1)), w2)   (bn+relu fused into staging load)
    conv3x3_kernel<64, 1, 1><<<grid16, 256, 0, stream>>>(bufT, Trb2 + (size_t)i * 36864,
                                                         nullptr, stats + (2 * i) * 128,
                                                         rb_g1 + i * 64, rb_be1 + i * 64,
                                                         stats + (2 * i + 1) * 128, bufT2);
    // y = bn(t2) + y
    bn_apply_add_kernel<<<2048, 256, 0, stream>>>(bufT2, stats + (2 * i + 1) * 128,
                                                  rb_g2 + i * 64, rb_be2 + i * 64, src, bufY);
  }

  // x = bn(conv2(y)) + x    -> bufX
  conv3x3_kernel<64, 0, 1><<<grid16, 256, 0, stream>>>(bufY, Tc2, nullptr, nullptr, nullptr,
                                                       nullptr, stats + 32 * 128, bufT);
  bn_apply_add_kernel<<<2048, 256, 0, stream>>>(bufT, stats + 32 * 128, bn2_g, bn2_be, bufX, bufX);

  // dc2: x = relu(dcn(x)) -> bufY
  conv3x3_kernel<27, 0, 0><<<grid16, 256, 0, stream>>>(bufX, Tow2, dc2_ob, nullptr, nullptr,
                                                       nullptr, nullptr, bufT);
  dcn_kernel<64, 0><<<grid16, 256, 0, stream>>>(bufX, bufT, Tdw2, dc2_b, nullptr, nullptr, bufY);

  // dc3: x = relu(dcn(x)) -> bufX
  conv3x3_kernel<27, 0, 0><<<grid16, 256, 0, stream>>>(bufY, Tow3, dc3_ob, nullptr, nullptr,
                                                       nullptr, nullptr, bufT);
  dcn_kernel<64, 0><<<grid16, 256, 0, stream>>>(bufY, bufT, Tdw3, dc3_b, nullptr, nullptr, bufX);

  // dc4 + conv4 (fused) -> d_out
  conv3x3_kernel<27, 0, 0><<<grid16, 256, 0, stream>>>(bufX, Tow4, dc4_ob, nullptr, nullptr,
                                                       nullptr, nullptr, bufT);
  dcn_kernel<1, 1><<<grid16, 256, 0, stream>>>(bufX, bufT, dc4_w, dc4_b, conv4_w, conv4_b,
                                               (float*)d_out);
}

// Round 3
// 6202.297 us; speedup vs baseline: 6.5219x; 6.5219x over previous
//
#include <hip/hip_runtime.h>
#include <cmath>

// Problem constants (B=2, C=64, H=W=256)
static constexpr int Bn   = 2;
static constexpr int Cn   = 64;
static constexpr int Hn   = 256;
static constexpr int Wn   = 256;
static constexpr int HW   = Hn * Wn;          // 65536
static constexpr int CHW  = Cn * HW;          // 4194304
static constexpr int NCHW = Bn * CHW;         // 8388608
static constexpr int NPIX = Bn * HW;          // 131072
static constexpr float EPSv = 1e-5f;
static constexpr float INV_N = 1.0f / 131072.0f;   // BN count = B*H*W
static constexpr int NSLOT = 32;              // stats slot replication (anti-contention)
static constexpr int STSLOT = NSLOT * 128;    // floats per layer stats region

// ---------------------------------------------------------------------------
// Weight transpose: in[nb][oc][ic][k] -> out[nb][(ic*K+k)*OC + oc]
// ---------------------------------------------------------------------------
__global__ void transpose_w_kernel(const float* __restrict__ in, float* __restrict__ out,
                                   int NB, int OC, int IC, int K) {
  int total = NB * OC * IC * K;
  for (int i = blockIdx.x * blockDim.x + threadIdx.x; i < total; i += gridDim.x * blockDim.x) {
    int k  = i % K;
    int t  = i / K;
    int ic = t % IC; t /= IC;
    int oc = t % OC;
    int nb = t / OC;
    out[(((size_t)nb * IC + ic) * K + k) * OC + oc] = in[i];
  }
}

// ---------------------------------------------------------------------------
// Prep: error = conv0(concat(Slope,Dist,Level)) (1x1), masked; x0 = ...
// ---------------------------------------------------------------------------
__global__ void prep_kernel(const float* __restrict__ LowDEM, const float* __restrict__ Point_Ele,
                            const float* __restrict__ Slope, const float* __restrict__ Distance,
                            const float* __restrict__ Level, const float* __restrict__ w0,
                            const float* __restrict__ b0, float* __restrict__ x0) {
  int i = blockIdx.x * blockDim.x + threadIdx.x;
  if (i >= NPIX) return;
  float lv  = Level[i];
  float err = w0[0] * Slope[i] + w0[1] * Distance[i] + w0[2] * lv + b0[0];
  float lm  = (lv != 0.0f) ? 1.0f : 0.0f;
  x0[i] = LowDEM[i] * (1.0f - lm) + Point_Ele[i] + err * lm;
}

// ---------------------------------------------------------------------------
// conv1: 9x9, 1 -> 64 channels, pad 4.  wT layout: [tap(81)][oc(64)]
// ---------------------------------------------------------------------------
__global__ __launch_bounds__(256, 2)
void conv9x9_kernel(const float* __restrict__ in, const float* __restrict__ wT,
                    const float* __restrict__ bias, float* __restrict__ out) {
  const int tx = threadIdx.x & 15, ty = threadIdx.x >> 4;
  const int w0 = blockIdx.x * 16, h0 = blockIdx.y * 16, b = blockIdx.z;
  __shared__ float lds[24 * 24];
  for (int idx = threadIdx.x; idx < 576; idx += 256) {
    int yy = idx / 24, xx = idx - yy * 24;
    int gy = h0 + yy - 4, gx = w0 + xx - 4;
    float v = 0.0f;
    if ((unsigned)gy < 256u && (unsigned)gx < 256u) v = in[b * HW + gy * 256 + gx];
    lds[idx] = v;
  }
  __syncthreads();
  float acc[64];
#pragma unroll
  for (int o = 0; o < 64; o++) acc[o] = 0.0f;
#pragma unroll 1
  for (int i = 0; i < 9; i++) {
#pragma unroll
    for (int j = 0; j < 9; j++) {
      float v = lds[(ty + i) * 24 + tx + j];
      const float* wp = wT + (i * 9 + j) * 64;   // uniform address -> s_load
#pragma unroll
      for (int o = 0; o < 64; o++) acc[o] = fmaf(v, wp[o], acc[o]);
    }
  }
  const int p = (h0 + ty) * 256 + (w0 + tx);
  float* op = out + (size_t)b * CHW + p;
#pragma unroll
  for (int o = 0; o < 64; o++) op[o * HW] = acc[o] + bias[o];
}

// ---------------------------------------------------------------------------
// conv3x3: 64 -> OCB*NSPLIT channels, pad 1. Each block computes OCB channels
// (half = blockIdx.z % NSPLIT). Grid z = b*NSPLIT + half.
// wT layout: [(ic*9+tap)*OC + oc]  (OC contiguous -> uniform scalar loads)
// BNIN==1: input is raw conv output t; apply r = relu(t*scale+shift) on the
//          LDS staging load; stats_in is a 32-slot region (summed in preamble).
// STATS==1: fused BN stats for the OUTPUT: wave shuffle-reduce -> LDS block
//           reduce -> 64 atomics/block scattered over 32 slots (128 lines).
//           R2 lesson: contention depth counts in CACHE LINES — per-wave
//           atomics to one 512B region serialized at ~158 ns/atomic = 41 ms.
// ---------------------------------------------------------------------------
template <int OCB, int NSP, int BNIN, int STATS>
__global__ __launch_bounds__(256, 4)
void conv3x3_kernel(const float* __restrict__ in, const float* __restrict__ wT,
                    const float* __restrict__ bias, const float* __restrict__ stats_in,
                    const float* __restrict__ g, const float* __restrict__ be,
                    float* __restrict__ stats_out, float* __restrict__ out) {
  const int OC = OCB * NSP;
  const int tx = threadIdx.x & 15, ty = threadIdx.x >> 4;
  const int lane = threadIdx.x & 63;
  const int wid = threadIdx.x >> 6;
  const int w0 = blockIdx.x * 16, h0 = blockIdx.y * 16;
  const int b = blockIdx.z / NSP, half = blockIdx.z % NSP;
  const int ocbase = half * OCB;
  __shared__ float lds[16][324];     // 16 channels x 18x18 tile
  __shared__ float s_sc[64], s_sh[64];
  __shared__ float red[STATS ? 8 * OCB : 1];   // [wave][sum/sumsq][OCB]
  if (BNIN) {
    if (threadIdx.x < 64) {
      int c = threadIdx.x;
      float sum = 0.0f, sq = 0.0f;
      for (int sl = 0; sl < NSLOT; sl++) {     // sum replicated slots (hot L2)
        sum += stats_in[sl * 128 + c];
        sq  += stats_in[sl * 128 + 64 + c];
      }
      float m   = sum * INV_N;
      float var = sq * INV_N - m * m;
      float s   = g[c] * rsqrtf(var + EPSv);
      s_sc[c] = s;
      s_sh[c] = be[c] - m * s;
    }
  }
  float acc[OCB];
#pragma unroll
  for (int o = 0; o < OCB; o++) acc[o] = 0.0f;
  const float* inb = in + (size_t)b * CHW;
  for (int cb = 0; cb < 64; cb += 16) {
    __syncthreads();
    for (int idx = threadIdx.x; idx < 16 * 324; idx += 256) {
      int c  = idx / 324;
      int r  = idx - c * 324;
      int yy = r / 18, xx = r - yy * 18;
      int gy = h0 + yy - 1, gx = w0 + xx - 1;
      float v = 0.0f;
      if ((unsigned)gy < 256u && (unsigned)gx < 256u) {
        v = inb[(cb + c) * HW + gy * 256 + gx];
        if (BNIN) v = fmaxf(fmaf(v, s_sc[cb + c], s_sh[cb + c]), 0.0f);
      }
      lds[c][r] = v;
    }
    __syncthreads();
#pragma unroll 1
    for (int c = 0; c < 16; c++) {
      const float* wp = wT + ((cb + c) * 9) * OC + ocbase;   // uniform -> s_load
#pragma unroll
      for (int t = 0; t < 9; t++) {
        float v = lds[c][(ty + t / 3) * 18 + tx + t % 3];
#pragma unroll
        for (int o = 0; o < OCB; o++) acc[o] = fmaf(v, wp[t * OC + o], acc[o]);
      }
    }
  }
  const int p = (h0 + ty) * 256 + (w0 + tx);
  float* op = out + ((size_t)b * OC + ocbase) * HW + p;
#pragma unroll
  for (int o = 0; o < OCB; o++) {
    float v = acc[o];
    if (bias) v += bias[ocbase + o];
    op[o * HW] = v;
    if (STATS) {
      float s = v, s2 = v * v;
#pragma unroll
      for (int off = 32; off > 0; off >>= 1) {
        s  += __shfl_down(s, off, 64);
        s2 += __shfl_down(s2, off, 64);
      }
      if (lane == 0) { red[(wid * 2 + 0) * OCB + o] = s; red[(wid * 2 + 1) * OCB + o] = s2; }
    }
  }
  if (STATS) {
    __syncthreads();
    if (threadIdx.x < 2 * OCB) {
      int o = threadIdx.x % OCB, which = threadIdx.x / OCB;
      float t = red[(0 * 2 + which) * OCB + o] + red[(1 * 2 + which) * OCB + o] +
                red[(2 * 2 + which) * OCB + o] + red[(3 * 2 + which) * OCB + o];
      int slot = (blockIdx.y * 16 + blockIdx.x) & (NSLOT - 1);
      atomicAdd(&stats_out[slot * 128 + which * 64 + ocbase + o], t);
    }
  }
}

// ---------------------------------------------------------------------------
// y = BN(t)*g+be + skip   (vectorized float4; slot-summed stats in preamble)
// ---------------------------------------------------------------------------
__global__ void bn_apply_add_kernel(const float* __restrict__ t, const float* __restrict__ stats,
                                    const float* __restrict__ g, const float* __restrict__ be,
                                    const float* __restrict__ skip, float* __restrict__ out) {
  __shared__ float s_sc[64], s_sh[64];
  if (threadIdx.x < 64) {
    int c = threadIdx.x;
    float sum = 0.0f, sq = 0.0f;
    for (int sl = 0; sl < NSLOT; sl++) {
      sum += stats[sl * 128 + c];
      sq  += stats[sl * 128 + 64 + c];
    }
    float m   = sum * INV_N;
    float var = sq * INV_N - m * m;
    float s   = g[c] * rsqrtf(var + EPSv);
    s_sc[c] = s;
    s_sh[c] = be[c] - m * s;
  }
  __syncthreads();
  const float4* t4 = (const float4*)t;
  const float4* k4 = (const float4*)skip;
  float4* o4 = (float4*)out;
  const int n4 = NCHW / 4;
  for (int i = blockIdx.x * blockDim.x + threadIdx.x; i < n4; i += gridDim.x * blockDim.x) {
    int c = (i >> 14) & 63;     // HW/4 = 16384 vec4 per channel
    float s = s_sc[c], h = s_sh[c];
    float4 v = t4[i], kk = k4[i], r;
    r.x = fmaf(v.x, s, h) + kk.x;
    r.y = fmaf(v.y, s, h) + kk.y;
    r.z = fmaf(v.z, s, h) + kk.z;
    r.w = fmaf(v.w, s, h) + kk.w;
    o4[i] = r;
  }
}

// ---------------------------------------------------------------------------
// Deformable conv main, chunked for cache locality:
//   for cb (16-ch chunks) { for k (9 taps) { recompute coeffs; 16x gather+FMA } }
// Working set per chunk ~23 KB -> cache-resident across the 9 taps (the R0
// version swept all 64 planes per tap -> 9x HBM re-fetch, 458 MB/dispatch).
// FINAL==1 (OC==1): fuse dc4 bias + conv4 1x1, write d_out (B,1,H,W).
// ---------------------------------------------------------------------------
template <int OC, int FINAL>
__global__ __launch_bounds__(256, 2)
void dcn_kernel(const float* __restrict__ x, const float* __restrict__ om,
                const float* __restrict__ wT, const float* __restrict__ bias,
                const float* __restrict__ c4w, const float* __restrict__ c4b,
                float* __restrict__ out) {
  const int tx = threadIdx.x & 15, ty = threadIdx.x >> 4;
  const int w0 = blockIdx.x * 16, h0 = blockIdx.y * 16, b = blockIdx.z;
  const int h = h0 + ty, w = w0 + tx;
  const int p = h * 256 + w;
  float acc[OC];
#pragma unroll
  for (int o = 0; o < OC; o++) acc[o] = 0.0f;
  const float* xb  = x + (size_t)b * CHW;
  const float* omb = om + (size_t)b * 27 * HW + p;
#pragma unroll 1
  for (int cb = 0; cb < 64; cb += 16) {
#pragma unroll 1
    for (int k = 0; k < 9; k++) {
      float dyv = omb[k * HW];
      float dxv = omb[(9 + k) * HW];
      float mo  = omb[(18 + k) * HW];
      float mk  = 1.0f / (1.0f + __expf(-mo));
      float ys = (float)(h + k / 3 - 1) + dyv;
      float xs = (float)(w + k % 3 - 1) + dxv;
      float y0f = floorf(ys), x0f = floorf(xs);
      float wy = ys - y0f, wx = xs - x0f;
      int y0 = (int)y0f, x0i = (int)x0f;
      int y1 = y0 + 1, x1 = x0i + 1;
      float vy0 = ((unsigned)y0  < 256u) ? 1.0f : 0.0f;
      float vy1 = ((unsigned)y1  < 256u) ? 1.0f : 0.0f;
      float vx0 = ((unsigned)x0i < 256u) ? 1.0f : 0.0f;
      float vx1 = ((unsigned)x1  < 256u) ? 1.0f : 0.0f;
      int cy0 = min(max(y0, 0), 255), cy1 = min(max(y1, 0), 255);
      int cx0 = min(max(x0i, 0), 255), cx1 = min(max(x1, 0), 255);
      int i00 = cy0 * 256 + cx0, i01 = cy0 * 256 + cx1;
      int i10 = cy1 * 256 + cx0, i11 = cy1 * 256 + cx1;
      float W00 = (1.0f - wy) * (1.0f - wx) * mk * vy0 * vx0;
      float W01 = (1.0f - wy) * wx * mk * vy0 * vx1;
      float W10 = wy * (1.0f - wx) * mk * vy1 * vx0;
      float W11 = wy * wx * mk * vy1 * vx1;
#pragma unroll 2
      for (int c = 0; c < 16; c++) {
        const float* xc = xb + (cb + c) * HW;
        float sv = W00 * xc[i00] + W01 * xc[i01] + W10 * xc[i10] + W11 * xc[i11];
        const float* wp = wT + ((cb + c) * 9 + k) * OC;   // uniform -> s_load
#pragma unroll
        for (int o = 0; o < OC; o++) acc[o] = fmaf(sv, wp[o], acc[o]);
      }
    }
  }
  if (FINAL) {
    float v = acc[0] + bias[0];
    out[(size_t)b * HW + p] = c4w[0] * v + c4b[0];
  } else {
    float* op = out + (size_t)b * OC * HW + p;
#pragma unroll
    for (int o = 0; o < OC; o++) op[o * HW] = fmaxf(acc[o] + bias[o], 0.0f);
  }
}

// ---------------------------------------------------------------------------
extern "C" void kernel_launch(void* const* d_in, const int* in_sizes, int n_in,
                              void* d_out, int out_size, void* d_ws, size_t ws_size,
                              hipStream_t stream) {
  const float* LowDEM    = (const float*)d_in[0];
  const float* Point_Ele = (const float*)d_in[1];
  const float* Slope     = (const float*)d_in[2];
  const float* Distance  = (const float*)d_in[3];
  const float* Level     = (const float*)d_in[4];
  const float* conv0_w   = (const float*)d_in[5];
  const float* conv0_b   = (const float*)d_in[6];
  const float* conv1_w   = (const float*)d_in[7];
  const float* conv1_b   = (const float*)d_in[8];
  const float* rb_w1     = (const float*)d_in[9];
  const float* rb_g1     = (const float*)d_in[11];
  const float* rb_be1    = (const float*)d_in[12];
  const float* rb_w2     = (const float*)d_in[13];
  const float* rb_g2     = (const float*)d_in[15];
  const float* rb_be2    = (const float*)d_in[16];
  const float* conv2_w   = (const float*)d_in[17];
  const float* bn2_g     = (const float*)d_in[19];
  const float* bn2_be    = (const float*)d_in[20];
  const float* dc2_w     = (const float*)d_in[21];
  const float* dc2_b     = (const float*)d_in[22];
  const float* dc2_ow    = (const float*)d_in[23];
  const float* dc2_ob    = (const float*)d_in[24];
  const float* dc3_w     = (const float*)d_in[25];
  const float* dc3_b     = (const float*)d_in[26];
  const float* dc3_ow    = (const float*)d_in[27];
  const float* dc3_ob    = (const float*)d_in[28];
  const float* dc4_w     = (const float*)d_in[29];
  const float* dc4_b     = (const float*)d_in[30];
  const float* dc4_ow    = (const float*)d_in[31];
  const float* dc4_ob    = (const float*)d_in[32];
  const float* conv4_w   = (const float*)d_in[33];
  const float* conv4_b   = (const float*)d_in[34];

  float* Wp   = (float*)d_ws;
  float* bufX = Wp;                       // 8388608 floats each
  float* bufY = bufX + NCHW;
  float* bufT = bufY + NCHW;
  float* bufT2= bufT + NCHW;
  float* x0   = bufT2 + NCHW;             // 131072
  float* T1   = x0 + NPIX;                // 81*64   = 5184
  float* Trb1 = T1 + 5184;                // 16*576*64 = 589824
  float* Trb2 = Trb1 + 589824;
  float* Tc2  = Trb2 + 589824;            // 36864
  float* Tow2 = Tc2 + 36864;              // 576*27 = 15552
  float* Tow3 = Tow2 + 15552;
  float* Tow4 = Tow3 + 15552;
  float* Tdw2 = Tow4 + 15552;             // 36864
  float* Tdw3 = Tdw2 + 36864;
  float* stats= Tdw3 + 36864;             // 33 layers * 32 slots * 128 floats

  hipMemsetAsync(stats, 0, 33 * STSLOT * sizeof(float), stream);

  transpose_w_kernel<<<256, 256, 0, stream>>>(rb_w1,   Trb1, 16, 64, 64, 9);
  transpose_w_kernel<<<256, 256, 0, stream>>>(rb_w2,   Trb2, 16, 64, 64, 9);
  transpose_w_kernel<<<32,  256, 0, stream>>>(conv1_w, T1,    1, 64,  1, 81);
  transpose_w_kernel<<<64,  256, 0, stream>>>(conv2_w, Tc2,   1, 64, 64, 9);
  transpose_w_kernel<<<32,  256, 0, stream>>>(dc2_ow,  Tow2,  1, 27, 64, 9);
  transpose_w_kernel<<<32,  256, 0, stream>>>(dc3_ow,  Tow3,  1, 27, 64, 9);
  transpose_w_kernel<<<32,  256, 0, stream>>>(dc4_ow,  Tow4,  1, 27, 64, 9);
  transpose_w_kernel<<<64,  256, 0, stream>>>(dc2_w,   Tdw2,  1, 64, 64, 9);
  transpose_w_kernel<<<64,  256, 0, stream>>>(dc3_w,   Tdw3,  1, 64, 64, 9);

  prep_kernel<<<(NPIX + 255) / 256, 256, 0, stream>>>(LowDEM, Point_Ele, Slope, Distance,
                                                      Level, conv0_w, conv0_b, x0);

  dim3 grid16(16, 16, 2);    // full-OC kernels (dcn, offset convs, conv9x9)
  dim3 gridS(16, 16, 4);     // oc-split conv3x3 (z = b*2 + half)

  conv9x9_kernel<<<grid16, 256, 0, stream>>>(x0, T1, conv1_b, bufX);   // X in bufX

  for (int i = 0; i < 16; i++) {
    const float* src = (i == 0) ? bufX : bufY;
    // t1 = conv(y, w1)  (bias dropped: cancelled by BN); fused stats epilogue
    conv3x3_kernel<32, 2, 0, 1><<<gridS, 256, 0, stream>>>(src, Trb1 + (size_t)i * 36864,
                                                           nullptr, nullptr, nullptr, nullptr,
                                                           stats + (2 * i) * STSLOT, bufT);
    // t2 = conv(relu(bn(t1)), w2)   (bn+relu fused into staging load)
    conv3x3_kernel<32, 2, 1, 1><<<gridS, 256, 0, stream>>>(bufT, Trb2 + (size_t)i * 36864,
                                                           nullptr, stats + (2 * i) * STSLOT,
                                                           rb_g1 + i * 64, rb_be1 + i * 64,
                                                           stats + (2 * i + 1) * STSLOT, bufT2);
    // y = bn(t2) + y
    bn_apply_add_kernel<<<2048, 256, 0, stream>>>(bufT2, stats + (2 * i + 1) * STSLOT,
                                                  rb_g2 + i * 64, rb_be2 + i * 64, src, bufY);
  }

  // x = bn(conv2(y)) + x    -> bufX
  conv3x3_kernel<32, 2, 0, 1><<<gridS, 256, 0, stream>>>(bufY, Tc2, nullptr, nullptr, nullptr,
                                                         nullptr, stats + 32 * STSLOT, bufT);
  bn_apply_add_kernel<<<2048, 256, 0, stream>>>(bufT, stats + 32 * STSLOT, bn2_g, bn2_be,
                                                bufX, bufX);

  // dc2: x = relu(dcn(x)) -> bufY
  conv3x3_kernel<27, 1, 0, 0><<<grid16, 256, 0, stream>>>(bufX, Tow2, dc2_ob, nullptr, nullptr,
                                                          nullptr, nullptr, bufT);
  dcn_kernel<64, 0><<<grid16, 256, 0, stream>>>(bufX, bufT, Tdw2, dc2_b, nullptr, nullptr, bufY);

  // dc3: x = relu(dcn(x)) -> bufX
  conv3x3_kernel<27, 1, 0, 0><<<grid16, 256, 0, stream>>>(bufY, Tow3, dc3_ob, nullptr, nullptr,
                                                          nullptr, nullptr, bufT);
  dcn_kernel<64, 0><<<grid16, 256, 0, stream>>>(bufY, bufT, Tdw3, dc3_b, nullptr, nullptr, bufX);

  // dc4 + conv4 (fused) -> d_out
  conv3x3_kernel<27, 1, 0, 0><<<grid16, 256, 0, stream>>>(bufX, Tow4, dc4_ob, nullptr, nullptr,
                                                          nullptr, nullptr, bufT);
  dcn_kernel<1, 1><<<grid16, 256, 0, stream>>>(bufX, bufT, dc4_w, dc4_b, conv4_w, conv4_b,
                                               (float*)d_out);
}

// Round 4
// 4158.035 us; speedup vs baseline: 9.7284x; 1.4916x over previous
//
#include <hip/hip_runtime.h>
#include <cmath>

typedef unsigned short ushort_t;
typedef __attribute__((ext_vector_type(8))) short bf16x8;
typedef __attribute__((ext_vector_type(4))) float f32x4;

// Problem constants (B=2, C=64, H=W=256)
static constexpr int Bn   = 2;
static constexpr int Hn   = 256;
static constexpr int Wn   = 256;
static constexpr int HW   = Hn * Wn;          // 65536
static constexpr int CHW  = 64 * HW;          // 4194304
static constexpr int NCHW = Bn * CHW;         // 8388608
static constexpr int NPIX = Bn * HW;          // 131072
static constexpr float EPSv = 1e-5f;
static constexpr float INV_N = 1.0f / 131072.0f;   // BN count = B*H*W
static constexpr int NSLOT = 64;              // stats slot replication (anti-contention)
static constexpr int STSLOT = NSLOT * 128;    // floats per layer stats region
static constexpr int WFL = 73728;             // ushorts per weight-fragment layer slot

// bf16 round-to-nearest-even (no NaN inputs in this net)
__device__ inline uint32_t bf16_rne(float f) {
  uint32_t u = __float_as_uint(f);
  return (u + 0x7FFFu + ((u >> 16) & 1u)) >> 16;
}
// split f32 into bf16 hi/lo, packed (hi<<16)|lo
__device__ inline uint32_t pack_split(float v) {
  uint32_t hi = bf16_rne(v);
  float hif = __uint_as_float(hi << 16);
  uint32_t lo = bf16_rne(v - hif);
  return (hi << 16) | (lo & 0xFFFFu);
}

// ---------------------------------------------------------------------------
// Weight transpose: in[nb][oc][ic][k] -> out[nb][(ic*K+k)*OC + oc]
// (still used for conv9x9 and the dcn einsum weights)
// ---------------------------------------------------------------------------
__global__ void transpose_w_kernel(const float* __restrict__ in, float* __restrict__ out,
                                   int NB, int OC, int IC, int K) {
  int total = NB * OC * IC * K;
  for (int i = blockIdx.x * blockDim.x + threadIdx.x; i < total; i += gridDim.x * blockDim.x) {
    int k  = i % K;
    int t  = i / K;
    int ic = t % IC; t /= IC;
    int oc = t % OC;
    int nb = t / OC;
    out[(((size_t)nb * IC + ic) * K + k) * OC + oc] = in[i];
  }
}

// ---------------------------------------------------------------------------
// Weight fragment prep for MFMA conv: w[oc][ic][3][3] f32 ->
//   hi plane: idx = (((tap*2+ih)*NG + g)*64 + lane)*8 + j   (bf16 hi)
//   lo plane at +elems. oc = g*16+(lane&15), ic = ih*32+(lane>>4)*8+j.
// oc >= ocreal (offset-conv padding) -> 0.
// ---------------------------------------------------------------------------
__global__ void prep_wfrag(const float* __restrict__ w, ushort_t* __restrict__ out,
                           int NGp, int ocreal, int wlstride, int olstride) {
  int layer = blockIdx.y;
  int elems = 9 * 2 * NGp * 64 * 8;
  int idx = blockIdx.x * 256 + threadIdx.x;
  if (idx >= elems) return;
  int j = idx & 7, lane = (idx >> 3) & 63;
  int rest = idx >> 9;
  int g = rest % NGp; rest /= NGp;
  int ih = rest & 1, tap = rest >> 1;
  int oc = g * 16 + (lane & 15);
  int ic = ih * 32 + (lane >> 4) * 8 + j;
  float v = 0.0f;
  if (oc < ocreal) v = w[(size_t)layer * wlstride + (oc * 64 + ic) * 9 + tap];
  uint32_t hi = bf16_rne(v);
  float hif = __uint_as_float(hi << 16);
  uint32_t lo = bf16_rne(v - hif);
  out[(size_t)layer * olstride + idx] = (ushort_t)hi;
  out[(size_t)layer * olstride + elems + idx] = (ushort_t)lo;
}

// ---------------------------------------------------------------------------
// Prep: error = conv0(concat(Slope,Dist,Level)) (1x1), masked; x0 = ...
// ---------------------------------------------------------------------------
__global__ void prep_kernel(const float* __restrict__ LowDEM, const float* __restrict__ Point_Ele,
                            const float* __restrict__ Slope, const float* __restrict__ Distance,
                            const float* __restrict__ Level, const float* __restrict__ w0,
                            const float* __restrict__ b0, float* __restrict__ x0) {
  int i = blockIdx.x * blockDim.x + threadIdx.x;
  if (i >= NPIX) return;
  float lv  = Level[i];
  float err = w0[0] * Slope[i] + w0[1] * Distance[i] + w0[2] * lv + b0[0];
  float lm  = (lv != 0.0f) ? 1.0f : 0.0f;
  x0[i] = LowDEM[i] * (1.0f - lm) + Point_Ele[i] + err * lm;
}

// ---------------------------------------------------------------------------
// conv1: 9x9, 1 -> 64 channels, pad 4.  wT layout: [tap(81)][oc(64)]
// ---------------------------------------------------------------------------
__global__ __launch_bounds__(256, 2)
void conv9x9_kernel(const float* __restrict__ in, const float* __restrict__ wT,
                    const float* __restrict__ bias, float* __restrict__ out) {
  const int tx = threadIdx.x & 15, ty = threadIdx.x >> 4;
  const int w0 = blockIdx.x * 16, h0 = blockIdx.y * 16, b = blockIdx.z;
  __shared__ float lds[24 * 24];
  for (int idx = threadIdx.x; idx < 576; idx += 256) {
    int yy = idx / 24, xx = idx - yy * 24;
    int gy = h0 + yy - 4, gx = w0 + xx - 4;
    float v = 0.0f;
    if ((unsigned)gy < 256u && (unsigned)gx < 256u) v = in[b * HW + gy * 256 + gx];
    lds[idx] = v;
  }
  __syncthreads();
  float acc[64];
#pragma unroll
  for (int o = 0; o < 64; o++) acc[o] = 0.0f;
#pragma unroll 1
  for (int i = 0; i < 9; i++) {
#pragma unroll
    for (int j = 0; j < 9; j++) {
      float v = lds[(ty + i) * 24 + tx + j];
      const float* wp = wT + (i * 9 + j) * 64;   // uniform address -> s_load
#pragma unroll
      for (int o = 0; o < 64; o++) acc[o] = fmaf(v, wp[o], acc[o]);
    }
  }
  const int p = (h0 + ty) * 256 + (w0 + tx);
  float* op = out + (size_t)b * CHW + p;
#pragma unroll
  for (int o = 0; o < 64; o++) op[o * HW] = acc[o] + bias[o];
}

// ---------------------------------------------------------------------------
// MFMA conv3x3 (implicit GEMM, 3-term bf16 hi/lo split ~ f32 accuracy).
// Block: 16x4 pixel tile x (NG*16) oc. Wave w = pixel row w. K = 9 taps x 64 ic.
// Fragment layouts (guide, m89/m120-verified):
//   A[m=lane&15][k=quad*8+j], B[n=lane&15][k=quad*8+j], D[row=quad*4+r][col=lane&15]
// x tile staged pre-split in LDS as packed (hi16|lo16) dwords, ic-stride 110
// (pad -> 2-way-free banks); weights staged per-tap (fragment-ordered, b128 reads).
// BNIN: relu(t*sc+sh) on staging load (zero pad applied after, as reference).
// STATS: per-oc sum/sumsq; wave-shuffle + LDS reduce + slot-scattered atomics.
// ---------------------------------------------------------------------------
template <int NG, int BNIN, int STATS, int OCLIM, int HASBIAS>
__global__ __launch_bounds__(256, 3)
void mfma_conv3(const float* __restrict__ in, const ushort_t* __restrict__ wf,
                const float* __restrict__ bias, const float* __restrict__ stats_in,
                const float* __restrict__ gg, const float* __restrict__ be,
                float* __restrict__ stats_out, float* __restrict__ out) {
  const int tid  = threadIdx.x;
  const int lane = tid & 63, wid = tid >> 6;
  const int m = lane & 15, quad = lane >> 4;
  const int x0 = blockIdx.x * 16, y0 = blockIdx.y * 4, b = blockIdx.z;
  constexpr int WT = 2 * NG * 64 * 8;          // ushorts per tap per plane
  __shared__ uint32_t xls[64 * 110];           // 28.2 KB packed hi|lo
  __shared__ ushort_t wls[2][WT];              // per-tap weights hi/lo
  __shared__ float s_sc[BNIN ? 64 : 1], s_sh[BNIN ? 64 : 1];
  __shared__ float red[STATS ? 2 * 4 * 64 : 1];
  if (BNIN) {
    if (tid < 64) {
      float sum = 0.0f, sq = 0.0f;
      for (int sl = 0; sl < NSLOT; sl++) {
        sum += stats_in[sl * 128 + tid];
        sq  += stats_in[sl * 128 + 64 + tid];
      }
      float mn = sum * INV_N, var = sq * INV_N - mn * mn;
      float s = gg[tid] * rsqrtf(var + EPSv);
      s_sc[tid] = s;
      s_sh[tid] = be[tid] - mn * s;
    }
    __syncthreads();
  }
  // stage x tile: 64 ic x rows[y0-1..y0+4] x cols[x0-1..x0+16], split+packed
  const float* inb = in + (size_t)b * CHW;
#pragma unroll
  for (int t = 0; t < 27; t++) {
    int idx = t * 256 + tid;                   // 27*256 == 64*108
    int ic = idx / 108, r = idx - ic * 108;
    int row = r / 18, col = r - row * 18;
    int gy = y0 - 1 + row, gx = x0 - 1 + col;
    float v = 0.0f;
    if ((unsigned)gy < 256u && (unsigned)gx < 256u) {
      v = inb[ic * HW + gy * 256 + gx];
      if (BNIN) v = fmaxf(fmaf(v, s_sc[ic], s_sh[ic]), 0.0f);
    }
    xls[ic * 110 + r] = pack_split(v);
  }
  f32x4 acc[NG];
#pragma unroll
  for (int g = 0; g < NG; g++) acc[g] = (f32x4){0.0f, 0.0f, 0.0f, 0.0f};

#pragma unroll 1
  for (int tap = 0; tap < 9; tap++) {
    __syncthreads();                           // protect previous tap's wls
    {
      const uint32_t* srch = (const uint32_t*)(wf + tap * WT);
      const uint32_t* srcl = (const uint32_t*)(wf + 9 * WT + tap * WT);
      uint32_t* dsth = (uint32_t*)&wls[0][0];
      uint32_t* dstl = (uint32_t*)&wls[1][0];
      for (int t = tid; t < WT / 2; t += 256) { dsth[t] = srch[t]; dstl[t] = srcl[t]; }
    }
    __syncthreads();
    const int dy = tap / 3 - 1, dx = tap % 3 - 1;
    const int spat = (wid + dy + 1) * 18 + (m + dx + 1);
#pragma unroll
    for (int ih = 0; ih < 2; ih++) {
      const int icb = ih * 32 + quad * 8;
      uint32_t d[8];
#pragma unroll
      for (int j = 0; j < 8; j++) d[j] = xls[(icb + j) * 110 + spat];
      union { bf16x8 v; uint32_t u[4]; } ah, al;
#pragma unroll
      for (int t = 0; t < 4; t++) {
        ah.u[t] = __builtin_amdgcn_perm(d[2 * t + 1], d[2 * t], 0x07060302u);
        al.u[t] = __builtin_amdgcn_perm(d[2 * t + 1], d[2 * t], 0x05040100u);
      }
#pragma unroll
      for (int g = 0; g < NG; g++) {
        bf16x8 bh = *(const bf16x8*)&wls[0][((ih * NG + g) * 64 + lane) * 8];
        bf16x8 bl = *(const bf16x8*)&wls[1][((ih * NG + g) * 64 + lane) * 8];
        acc[g] = __builtin_amdgcn_mfma_f32_16x16x32_bf16(ah.v, bh, acc[g], 0, 0, 0);
        acc[g] = __builtin_amdgcn_mfma_f32_16x16x32_bf16(al.v, bh, acc[g], 0, 0, 0);
        acc[g] = __builtin_amdgcn_mfma_f32_16x16x32_bf16(ah.v, bl, acc[g], 0, 0, 0);
      }
    }
  }
  // epilogue: D[row=quad*4+r][col=lane&15] -> pixel (y0+wid, x0+quad*4+r), oc=g*16+m
  const int py = y0 + wid;
  float* ob = out + (size_t)b * OCLIM * HW + py * 256 + x0 + quad * 4;
#pragma unroll
  for (int g = 0; g < NG; g++) {
    int oc = g * 16 + m;
    if (oc < OCLIM) {
      float bv = HASBIAS ? bias[oc] : 0.0f;
#pragma unroll
      for (int r = 0; r < 4; r++) ob[oc * HW + r] = acc[g][r] + bv;
    }
    if (STATS) {
      float s  = acc[g][0] + acc[g][1] + acc[g][2] + acc[g][3];
      float s2 = acc[g][0] * acc[g][0] + acc[g][1] * acc[g][1] +
                 acc[g][2] * acc[g][2] + acc[g][3] * acc[g][3];
      s  += __shfl_xor(s, 16, 64);  s  += __shfl_xor(s, 32, 64);
      s2 += __shfl_xor(s2, 16, 64); s2 += __shfl_xor(s2, 32, 64);
      if (lane < 16) {
        red[(0 * 4 + wid) * 64 + g * 16 + lane] = s;
        red[(1 * 4 + wid) * 64 + g * 16 + lane] = s2;
      }
    }
  }
  if (STATS) {
    __syncthreads();
    if (tid < 128) {
      int oc = tid & 63, which = tid >> 6;
      float tot = red[(which * 4 + 0) * 64 + oc] + red[(which * 4 + 1) * 64 + oc] +
                  red[(which * 4 + 2) * 64 + oc] + red[(which * 4 + 3) * 64 + oc];
      int slot = (blockIdx.y * 16 + blockIdx.x) & (NSLOT - 1);
      atomicAdd(&stats_out[slot * 128 + which * 64 + oc], tot);
    }
  }
}

// ---------------------------------------------------------------------------
// y = BN(t)*g+be + skip   (vectorized float4; slot-summed stats in preamble)
// ---------------------------------------------------------------------------
__global__ void bn_apply_add_kernel(const float* __restrict__ t, const float* __restrict__ stats,
                                    const float* __restrict__ g, const float* __restrict__ be,
                                    const float* __restrict__ skip, float* __restrict__ out) {
  __shared__ float s_sc[64], s_sh[64];
  if (threadIdx.x < 64) {
    int c = threadIdx.x;
    float sum = 0.0f, sq = 0.0f;
    for (int sl = 0; sl < NSLOT; sl++) {
      sum += stats[sl * 128 + c];
      sq  += stats[sl * 128 + 64 + c];
    }
    float m   = sum * INV_N;
    float var = sq * INV_N - m * m;
    float s   = g[c] * rsqrtf(var + EPSv);
    s_sc[c] = s;
    s_sh[c] = be[c] - m * s;
  }
  __syncthreads();
  const float4* t4 = (const float4*)t;
  const float4* k4 = (const float4*)skip;
  float4* o4 = (float4*)out;
  const int n4 = NCHW / 4;
  for (int i = blockIdx.x * blockDim.x + threadIdx.x; i < n4; i += gridDim.x * blockDim.x) {
    int c = (i >> 14) & 63;
    float s = s_sc[c], h = s_sh[c];
    float4 v = t4[i], kk = k4[i], r;
    r.x = fmaf(v.x, s, h) + kk.x;
    r.y = fmaf(v.y, s, h) + kk.y;
    r.z = fmaf(v.z, s, h) + kk.z;
    r.w = fmaf(v.w, s, h) + kk.w;
    o4[i] = r;
  }
}

// ---------------------------------------------------------------------------
// Deformable conv main, chunked for cache locality. Offsets clamped to
// [-2,258] (identical result in-range; bounds gather spread for any garbage
// offsets -- kills the 41 ms profile-replay straggler artifact).
// FINAL==1 (OC==1): fuse dc4 bias + conv4 1x1, write d_out (B,1,H,W).
// ---------------------------------------------------------------------------
template <int OC, int FINAL>
__global__ __launch_bounds__(256, 2)
void dcn_kernel(const float* __restrict__ x, const float* __restrict__ om,
                const float* __restrict__ wT, const float* __restrict__ bias,
                const float* __restrict__ c4w, const float* __restrict__ c4b,
                float* __restrict__ out) {
  const int tx = threadIdx.x & 15, ty = threadIdx.x >> 4;
  const int w0 = blockIdx.x * 16, h0 = blockIdx.y * 16, b = blockIdx.z;
  const int h = h0 + ty, w = w0 + tx;
  const int p = h * 256 + w;
  float acc[OC];
#pragma unroll
  for (int o = 0; o < OC; o++) acc[o] = 0.0f;
  const float* xb  = x + (size_t)b * CHW;
  const float* omb = om + (size_t)b * 27 * HW + p;
#pragma unroll 1
  for (int cb = 0; cb < 64; cb += 16) {
#pragma unroll 1
    for (int k = 0; k < 9; k++) {
      float dyv = omb[k * HW];
      float dxv = omb[(9 + k) * HW];
      float mo  = omb[(18 + k) * HW];
      float mk  = 1.0f / (1.0f + __expf(-mo));
      float ys = (float)(h + k / 3 - 1) + dyv;
      float xs = (float)(w + k % 3 - 1) + dxv;
      ys = fminf(fmaxf(ys, -2.0f), 258.0f);
      xs = fminf(fmaxf(xs, -2.0f), 258.0f);
      float y0f = floorf(ys), x0f = floorf(xs);
      float wy = ys - y0f, wx = xs - x0f;
      int y0 = (int)y0f, x0i = (int)x0f;
      int y1 = y0 + 1, x1 = x0i + 1;
      float vy0 = ((unsigned)y0  < 256u) ? 1.0f : 0.0f;
      float vy1 = ((unsigned)y1  < 256u) ? 1.0f : 0.0f;
      float vx0 = ((unsigned)x0i < 256u) ? 1.0f : 0.0f;
      float vx1 = ((unsigned)x1  < 256u) ? 1.0f : 0.0f;
      int cy0 = min(max(y0, 0), 255), cy1 = min(max(y1, 0), 255);
      int cx0 = min(max(x0i, 0), 255), cx1 = min(max(x1, 0), 255);
      int i00 = cy0 * 256 + cx0, i01 = cy0 * 256 + cx1;
      int i10 = cy1 * 256 + cx0, i11 = cy1 * 256 + cx1;
      float W00 = (1.0f - wy) * (1.0f - wx) * mk * vy0 * vx0;
      float W01 = (1.0f - wy) * wx * mk * vy0 * vx1;
      float W10 = wy * (1.0f - wx) * mk * vy1 * vx0;
      float W11 = wy * wx * mk * vy1 * vx1;
#pragma unroll 2
      for (int c = 0; c < 16; c++) {
        const float* xc = xb + (cb + c) * HW;
        float sv = W00 * xc[i00] + W01 * xc[i01] + W10 * xc[i10] + W11 * xc[i11];
        const float* wp = wT + ((cb + c) * 9 + k) * OC;   // uniform -> s_load
#pragma unroll
        for (int o = 0; o < OC; o++) acc[o] = fmaf(sv, wp[o], acc[o]);
      }
    }
  }
  if (FINAL) {
    float v = acc[0] + bias[0];
    out[(size_t)b * HW + p] = c4w[0] * v + c4b[0];
  } else {
    float* op = out + (size_t)b * OC * HW + p;
#pragma unroll
    for (int o = 0; o < OC; o++) op[o * HW] = fmaxf(acc[o] + bias[o], 0.0f);
  }
}

// ---------------------------------------------------------------------------
extern "C" void kernel_launch(void* const* d_in, const int* in_sizes, int n_in,
                              void* d_out, int out_size, void* d_ws, size_t ws_size,
                              hipStream_t stream) {
  const float* LowDEM    = (const float*)d_in[0];
  const float* Point_Ele = (const float*)d_in[1];
  const float* Slope     = (const float*)d_in[2];
  const float* Distance  = (const float*)d_in[3];
  const float* Level     = (const float*)d_in[4];
  const float* conv0_w   = (const float*)d_in[5];
  const float* conv0_b   = (const float*)d_in[6];
  const float* conv1_w   = (const float*)d_in[7];
  const float* conv1_b   = (const float*)d_in[8];
  const float* rb_w1     = (const float*)d_in[9];
  const float* rb_g1     = (const float*)d_in[11];
  const float* rb_be1    = (const float*)d_in[12];
  const float* rb_w2     = (const float*)d_in[13];
  const float* rb_g2     = (const float*)d_in[15];
  const float* rb_be2    = (const float*)d_in[16];
  const float* conv2_w   = (const float*)d_in[17];
  const float* bn2_g     = (const float*)d_in[19];
  const float* bn2_be    = (const float*)d_in[20];
  const float* dc2_w     = (const float*)d_in[21];
  const float* dc2_b     = (const float*)d_in[22];
  const float* dc2_ow    = (const float*)d_in[23];
  const float* dc2_ob    = (const float*)d_in[24];
  const float* dc3_w     = (const float*)d_in[25];
  const float* dc3_b     = (const float*)d_in[26];
  const float* dc3_ow    = (const float*)d_in[27];
  const float* dc3_ob    = (const float*)d_in[28];
  const float* dc4_w     = (const float*)d_in[29];
  const float* dc4_b     = (const float*)d_in[30];
  const float* dc4_ow    = (const float*)d_in[31];
  const float* dc4_ob    = (const float*)d_in[32];
  const float* conv4_w   = (const float*)d_in[33];
  const float* conv4_b   = (const float*)d_in[34];

  float* bufX = (float*)d_ws;             // 8388608 floats each
  float* bufY = bufX + NCHW;
  float* bufT = bufY + NCHW;
  float* bufT2= bufT + NCHW;
  float* x0   = bufT2 + NCHW;             // 131072
  float* T1   = x0 + NPIX;                // 81*64 = 5184
  float* Tdw2 = T1 + 5184;                // 36864
  float* Tdw3 = Tdw2 + 36864;             // 36864
  ushort_t* WF = (ushort_t*)(Tdw3 + 36864);   // 36 layers * 73728 ushorts
  float* stats = (float*)(WF + 36 * WFL); // 33 layers * 64 slots * 128 floats

  hipMemsetAsync(stats, 0, 33 * STSLOT * sizeof(float), stream);

  transpose_w_kernel<<<32, 256, 0, stream>>>(conv1_w, T1,   1, 64,  1, 81);
  transpose_w_kernel<<<64, 256, 0, stream>>>(dc2_w,   Tdw2, 1, 64, 64, 9);
  transpose_w_kernel<<<64, 256, 0, stream>>>(dc3_w,   Tdw3, 1, 64, 64, 9);

  prep_wfrag<<<dim3(144, 16), 256, 0, stream>>>(rb_w1,   WF,            4, 64, 36864, WFL);
  prep_wfrag<<<dim3(144, 16), 256, 0, stream>>>(rb_w2,   WF + 16 * WFL, 4, 64, 36864, WFL);
  prep_wfrag<<<dim3(144, 1),  256, 0, stream>>>(conv2_w, WF + 32 * WFL, 4, 64, 36864, WFL);
  prep_wfrag<<<dim3(72, 1),   256, 0, stream>>>(dc2_ow,  WF + 33 * WFL, 2, 27, 15552, WFL);
  prep_wfrag<<<dim3(72, 1),   256, 0, stream>>>(dc3_ow,  WF + 34 * WFL, 2, 27, 15552, WFL);
  prep_wfrag<<<dim3(72, 1),   256, 0, stream>>>(dc4_ow,  WF + 35 * WFL, 2, 27, 15552, WFL);

  prep_kernel<<<(NPIX + 255) / 256, 256, 0, stream>>>(LowDEM, Point_Ele, Slope, Distance,
                                                      Level, conv0_w, conv0_b, x0);

  dim3 grid16(16, 16, 2);   // dcn / conv9x9
  dim3 gmf(16, 64, 2);      // mfma conv3x3 (16x4 pixel tiles)

  conv9x9_kernel<<<grid16, 256, 0, stream>>>(x0, T1, conv1_b, bufX);   // X in bufX

  for (int i = 0; i < 16; i++) {
    const float* src = (i == 0) ? bufX : bufY;
    // t1 = conv(y, w1) (bias cancelled by BN); fused stats
    mfma_conv3<4, 0, 1, 64, 0><<<gmf, 256, 0, stream>>>(
        src, WF + (size_t)i * WFL, nullptr, nullptr, nullptr, nullptr,
        stats + (2 * i) * STSLOT, bufT);
    // t2 = conv(relu(bn(t1)), w2) (bn+relu fused into staging)
    mfma_conv3<4, 1, 1, 64, 0><<<gmf, 256, 0, stream>>>(
        bufT, WF + (size_t)(16 + i) * WFL, nullptr, stats + (2 * i) * STSLOT,
        rb_g1 + i * 64, rb_be1 + i * 64, stats + (2 * i + 1) * STSLOT, bufT2);
    // y = bn(t2) + y
    bn_apply_add_kernel<<<2048, 256, 0, stream>>>(bufT2, stats + (2 * i + 1) * STSLOT,
                                                  rb_g2 + i * 64, rb_be2 + i * 64, src, bufY);
  }

  // x = bn(conv2(y)) + x    -> bufX
  mfma_conv3<4, 0, 1, 64, 0><<<gmf, 256, 0, stream>>>(
      bufY, WF + (size_t)32 * WFL, nullptr, nullptr, nullptr, nullptr,
      stats + 32 * STSLOT, bufT);
  bn_apply_add_kernel<<<2048, 256, 0, stream>>>(bufT, stats + 32 * STSLOT, bn2_g, bn2_be,
                                                bufX, bufX);

  // dc2: x = relu(dcn(x)) -> bufY
  mfma_conv3<2, 0, 0, 27, 1><<<gmf, 256, 0, stream>>>(
      bufX, WF + (size_t)33 * WFL, dc2_ob, nullptr, nullptr, nullptr, nullptr, bufT);
  dcn_kernel<64, 0><<<grid16, 256, 0, stream>>>(bufX, bufT, Tdw2, dc2_b, nullptr, nullptr, bufY);

  // dc3: x = relu(dcn(x)) -> bufX
  mfma_conv3<2, 0, 0, 27, 1><<<gmf, 256, 0, stream>>>(
      bufY, WF + (size_t)34 * WFL, dc3_ob, nullptr, nullptr, nullptr, nullptr, bufT);
  dcn_kernel<64, 0><<<grid16, 256, 0, stream>>>(bufY, bufT, Tdw3, dc3_b, nullptr, nullptr, bufX);

  // dc4 + conv4 (fused) -> d_out
  mfma_conv3<2, 0, 0, 27, 1><<<gmf, 256, 0, stream>>>(
      bufX, WF + (size_t)35 * WFL, dc4_ob, nullptr, nullptr, nullptr, nullptr, bufT);
  dcn_kernel<1, 1><<<grid16, 256, 0, stream>>>(bufX, bufT, dc4_w, dc4_b, conv4_w, conv4_b,
                                               (float*)d_out);
}

// Round 5
// 3219.196 us; speedup vs baseline: 12.5656x; 1.2916x over previous
//
#include <hip/hip_runtime.h>
#include <cmath>

typedef unsigned short ushort_t;
typedef __attribute__((ext_vector_type(8))) short bf16x8;
typedef __attribute__((ext_vector_type(4))) float f32x4;

// Problem constants (B=2, C=64, H=W=256)
static constexpr int Bn   = 2;
static constexpr int Hn   = 256;
static constexpr int Wn   = 256;
static constexpr int HW   = Hn * Wn;          // 65536
static constexpr int CHW  = 64 * HW;          // 4194304
static constexpr int NCHW = Bn * CHW;         // 8388608
static constexpr int NPIX = Bn * HW;          // 131072
static constexpr float EPSv = 1e-5f;
static constexpr float INV_N = 1.0f / 131072.0f;   // BN count = B*H*W
static constexpr int NSLOT = 64;              // stats slot replication (anti-contention)
static constexpr int STSLOT = NSLOT * 128;    // floats per layer stats region
static constexpr int WFL = 73728;             // ushorts per weight-fragment layer slot

// bf16 round-to-nearest-even (no NaN inputs in this net)
__device__ inline uint32_t bf16_rne(float f) {
  uint32_t u = __float_as_uint(f);
  return (u + 0x7FFFu + ((u >> 16) & 1u)) >> 16;
}
// split f32 into bf16 hi/lo, packed (hi<<16)|lo
__device__ inline uint32_t pack_split(float v) {
  uint32_t hi = bf16_rne(v);
  float hif = __uint_as_float(hi << 16);
  uint32_t lo = bf16_rne(v - hif);
  return (hi << 16) | (lo & 0xFFFFu);
}

// ---------------------------------------------------------------------------
// Weight transpose: in[nb][oc][ic][k] -> out[nb][(ic*K+k)*OC + oc]
// (used for conv9x9 and the dcn einsum weights)
// ---------------------------------------------------------------------------
__global__ void transpose_w_kernel(const float* __restrict__ in, float* __restrict__ out,
                                   int NB, int OC, int IC, int K) {
  int total = NB * OC * IC * K;
  for (int i = blockIdx.x * blockDim.x + threadIdx.x; i < total; i += gridDim.x * blockDim.x) {
    int k  = i % K;
    int t  = i / K;
    int ic = t % IC; t /= IC;
    int oc = t % OC;
    int nb = t / OC;
    out[(((size_t)nb * IC + ic) * K + k) * OC + oc] = in[i];
  }
}

// ---------------------------------------------------------------------------
// Weight fragment prep for MFMA conv: w[oc][ic][3][3] f32 ->
//   hi plane: idx = (((tap*2+ih)*NG + g)*64 + lane)*8 + j   (bf16 hi)
//   lo plane at +elems. oc = g*16+(lane&15), ic = ih*32+(lane>>4)*8+j.
// oc >= ocreal (offset-conv padding) -> 0.
// ---------------------------------------------------------------------------
__global__ void prep_wfrag(const float* __restrict__ w, ushort_t* __restrict__ out,
                           int NGp, int ocreal, int wlstride, int olstride) {
  int layer = blockIdx.y;
  int elems = 9 * 2 * NGp * 64 * 8;
  int idx = blockIdx.x * 256 + threadIdx.x;
  if (idx >= elems) return;
  int j = idx & 7, lane = (idx >> 3) & 63;
  int rest = idx >> 9;
  int g = rest % NGp; rest /= NGp;
  int ih = rest & 1, tap = rest >> 1;
  int oc = g * 16 + (lane & 15);
  int ic = ih * 32 + (lane >> 4) * 8 + j;
  float v = 0.0f;
  if (oc < ocreal) v = w[(size_t)layer * wlstride + (oc * 64 + ic) * 9 + tap];
  uint32_t hi = bf16_rne(v);
  float hif = __uint_as_float(hi << 16);
  uint32_t lo = bf16_rne(v - hif);
  out[(size_t)layer * olstride + idx] = (ushort_t)hi;
  out[(size_t)layer * olstride + elems + idx] = (ushort_t)lo;
}

// ---------------------------------------------------------------------------
// Prep: error = conv0(concat(Slope,Dist,Level)) (1x1), masked; x0 = ...
// ---------------------------------------------------------------------------
__global__ void prep_kernel(const float* __restrict__ LowDEM, const float* __restrict__ Point_Ele,
                            const float* __restrict__ Slope, const float* __restrict__ Distance,
                            const float* __restrict__ Level, const float* __restrict__ w0,
                            const float* __restrict__ b0, float* __restrict__ x0) {
  int i = blockIdx.x * blockDim.x + threadIdx.x;
  if (i >= NPIX) return;
  float lv  = Level[i];
  float err = w0[0] * Slope[i] + w0[1] * Distance[i] + w0[2] * lv + b0[0];
  float lm  = (lv != 0.0f) ? 1.0f : 0.0f;
  x0[i] = LowDEM[i] * (1.0f - lm) + Point_Ele[i] + err * lm;
}

// ---------------------------------------------------------------------------
// conv1: 9x9, 1 -> 64 channels, pad 4.  wT layout: [tap(81)][oc(64)]
// ---------------------------------------------------------------------------
__global__ __launch_bounds__(256, 2)
void conv9x9_kernel(const float* __restrict__ in, const float* __restrict__ wT,
                    const float* __restrict__ bias, float* __restrict__ out) {
  const int tx = threadIdx.x & 15, ty = threadIdx.x >> 4;
  const int w0 = blockIdx.x * 16, h0 = blockIdx.y * 16, b = blockIdx.z;
  __shared__ float lds[24 * 24];
  for (int idx = threadIdx.x; idx < 576; idx += 256) {
    int yy = idx / 24, xx = idx - yy * 24;
    int gy = h0 + yy - 4, gx = w0 + xx - 4;
    float v = 0.0f;
    if ((unsigned)gy < 256u && (unsigned)gx < 256u) v = in[b * HW + gy * 256 + gx];
    lds[idx] = v;
  }
  __syncthreads();
  float acc[64];
#pragma unroll
  for (int o = 0; o < 64; o++) acc[o] = 0.0f;
#pragma unroll 1
  for (int i = 0; i < 9; i++) {
#pragma unroll
    for (int j = 0; j < 9; j++) {
      float v = lds[(ty + i) * 24 + tx + j];
      const float* wp = wT + (i * 9 + j) * 64;   // uniform address -> s_load
#pragma unroll
      for (int o = 0; o < 64; o++) acc[o] = fmaf(v, wp[o], acc[o]);
    }
  }
  const int p = (h0 + ty) * 256 + (w0 + tx);
  float* op = out + (size_t)b * CHW + p;
#pragma unroll
  for (int o = 0; o < 64; o++) op[o * HW] = acc[o] + bias[o];
}

// ---------------------------------------------------------------------------
// MFMA conv3x3 (implicit GEMM, 3-term bf16 hi/lo split ~ f32 accuracy).
// Block: 16x4 pixel tile x (NG*16) oc. Wave w = pixel row w. K = 9 taps x 64 ic.
// R5: BARRIER-FREE K-loop — B-fragments loaded straight from global into
// registers (lane-contiguous b128, identical across waves -> L1-served); the
// R4 per-tap global->LDS weight stage had 2 barriers/tap (18/block), each
// draining vmcnt(0)+lgkmcnt(0) for all waves (the m97-style structural stall).
// A path unchanged from R4 (packed hi|lo dwords in LDS, stride 110 = 2-way-free).
// ---------------------------------------------------------------------------
template <int NG, int BNIN, int STATS, int OCLIM, int HASBIAS>
__global__ __launch_bounds__(256, 3)
void mfma_conv3(const float* __restrict__ in, const ushort_t* __restrict__ wf,
                const float* __restrict__ bias, const float* __restrict__ stats_in,
                const float* __restrict__ gg, const float* __restrict__ be,
                float* __restrict__ stats_out, float* __restrict__ out) {
  const int tid  = threadIdx.x;
  const int lane = tid & 63, wid = tid >> 6;
  const int m = lane & 15, quad = lane >> 4;
  const int x0 = blockIdx.x * 16, y0 = blockIdx.y * 4, b = blockIdx.z;
  constexpr int WT = 2 * NG * 64 * 8;          // ushorts per tap per plane
  __shared__ uint32_t xls[64 * 110];           // 28.2 KB packed hi|lo
  __shared__ float s_sc[BNIN ? 64 : 1], s_sh[BNIN ? 64 : 1];
  __shared__ float red[STATS ? 2 * 4 * 64 : 1];
  if (BNIN) {
    if (tid < 64) {
      float sum = 0.0f, sq = 0.0f;
      for (int sl = 0; sl < NSLOT; sl++) {
        sum += stats_in[sl * 128 + tid];
        sq  += stats_in[sl * 128 + 64 + tid];
      }
      float mn = sum * INV_N, var = sq * INV_N - mn * mn;
      float s = gg[tid] * rsqrtf(var + EPSv);
      s_sc[tid] = s;
      s_sh[tid] = be[tid] - mn * s;
    }
    __syncthreads();
  }
  // stage x tile: 64 ic x rows[y0-1..y0+4] x cols[x0-1..x0+16], split+packed
  const float* inb = in + (size_t)b * CHW;
#pragma unroll
  for (int t = 0; t < 27; t++) {
    int idx = t * 256 + tid;                   // 27*256 == 64*108
    int ic = idx / 108, r = idx - ic * 108;
    int row = r / 18, col = r - row * 18;
    int gy = y0 - 1 + row, gx = x0 - 1 + col;
    float v = 0.0f;
    if ((unsigned)gy < 256u && (unsigned)gx < 256u) {
      v = inb[ic * HW + gy * 256 + gx];
      if (BNIN) v = fmaxf(fmaf(v, s_sc[ic], s_sh[ic]), 0.0f);
    }
    xls[ic * 110 + r] = pack_split(v);
  }
  __syncthreads();                             // the ONLY barrier before epilogue
  f32x4 acc[NG];
#pragma unroll
  for (int g = 0; g < NG; g++) acc[g] = (f32x4){0.0f, 0.0f, 0.0f, 0.0f};

  const bf16x8* wfh = (const bf16x8*)wf;                 // hi plane, frag-ordered
  const bf16x8* wfl = (const bf16x8*)(wf + 9 * WT);      // lo plane

#pragma unroll 1
  for (int tap = 0; tap < 9; tap++) {
    // issue ALL B loads for this tap first (global, L1-hot, vmcnt-overlapped)
    bf16x8 bh[2][NG], bl[2][NG];
#pragma unroll
    for (int ih = 0; ih < 2; ih++)
#pragma unroll
      for (int g = 0; g < NG; g++) {
        int fi = ((tap * 2 + ih) * NG + g) * 64 + lane;
        bh[ih][g] = wfh[fi];
        bl[ih][g] = wfl[fi];
      }
    const int dy = tap / 3 - 1, dx = tap % 3 - 1;
    const int spat = (wid + dy + 1) * 18 + (m + dx + 1);
#pragma unroll
    for (int ih = 0; ih < 2; ih++) {
      const int icb = ih * 32 + quad * 8;
      uint32_t d[8];
#pragma unroll
      for (int j = 0; j < 8; j++) d[j] = xls[(icb + j) * 110 + spat];
      union { bf16x8 v; uint32_t u[4]; } ah, al;
#pragma unroll
      for (int t = 0; t < 4; t++) {
        ah.u[t] = __builtin_amdgcn_perm(d[2 * t + 1], d[2 * t], 0x07060302u);
        al.u[t] = __builtin_amdgcn_perm(d[2 * t + 1], d[2 * t], 0x05040100u);
      }
#pragma unroll
      for (int g = 0; g < NG; g++) {
        acc[g] = __builtin_amdgcn_mfma_f32_16x16x32_bf16(ah.v, bh[ih][g], acc[g], 0, 0, 0);
        acc[g] = __builtin_amdgcn_mfma_f32_16x16x32_bf16(al.v, bh[ih][g], acc[g], 0, 0, 0);
        acc[g] = __builtin_amdgcn_mfma_f32_16x16x32_bf16(ah.v, bl[ih][g], acc[g], 0, 0, 0);
      }
    }
  }
  // epilogue: D[row=quad*4+r][col=lane&15] -> pixel (y0+wid, x0+quad*4+r), oc=g*16+m
  const int py = y0 + wid;
  float* ob = out + (size_t)b * OCLIM * HW + py * 256 + x0 + quad * 4;
#pragma unroll
  for (int g = 0; g < NG; g++) {
    int oc = g * 16 + m;
    if (oc < OCLIM) {
      float bv = HASBIAS ? bias[oc] : 0.0f;
#pragma unroll
      for (int r = 0; r < 4; r++) ob[oc * HW + r] = acc[g][r] + bv;
    }
    if (STATS) {
      float s  = acc[g][0] + acc[g][1] + acc[g][2] + acc[g][3];
      float s2 = acc[g][0] * acc[g][0] + acc[g][1] * acc[g][1] +
                 acc[g][2] * acc[g][2] + acc[g][3] * acc[g][3];
      s  += __shfl_xor(s, 16, 64);  s  += __shfl_xor(s, 32, 64);
      s2 += __shfl_xor(s2, 16, 64); s2 += __shfl_xor(s2, 32, 64);
      if (lane < 16) {
        red[(0 * 4 + wid) * 64 + g * 16 + lane] = s;
        red[(1 * 4 + wid) * 64 + g * 16 + lane] = s2;
      }
    }
  }
  if (STATS) {
    __syncthreads();
    if (tid < 128) {
      int oc = tid & 63, which = tid >> 6;
      float tot = red[(which * 4 + 0) * 64 + oc] + red[(which * 4 + 1) * 64 + oc] +
                  red[(which * 4 + 2) * 64 + oc] + red[(which * 4 + 3) * 64 + oc];
      int slot = (blockIdx.y * 16 + blockIdx.x) & (NSLOT - 1);
      atomicAdd(&stats_out[slot * 128 + which * 64 + oc], tot);
    }
  }
}

// ---------------------------------------------------------------------------
// y = BN(t)*g+be + skip   (vectorized float4; slot-summed stats in preamble)
// ---------------------------------------------------------------------------
__global__ void bn_apply_add_kernel(const float* __restrict__ t, const float* __restrict__ stats,
                                    const float* __restrict__ g, const float* __restrict__ be,
                                    const float* __restrict__ skip, float* __restrict__ out) {
  __shared__ float s_sc[64], s_sh[64];
  if (threadIdx.x < 64) {
    int c = threadIdx.x;
    float sum = 0.0f, sq = 0.0f;
    for (int sl = 0; sl < NSLOT; sl++) {
      sum += stats[sl * 128 + c];
      sq  += stats[sl * 128 + 64 + c];
    }
    float m   = sum * INV_N;
    float var = sq * INV_N - m * m;
    float s   = g[c] * rsqrtf(var + EPSv);
    s_sc[c] = s;
    s_sh[c] = be[c] - m * s;
  }
  __syncthreads();
  const float4* t4 = (const float4*)t;
  const float4* k4 = (const float4*)skip;
  float4* o4 = (float4*)out;
  const int n4 = NCHW / 4;
  for (int i = blockIdx.x * blockDim.x + threadIdx.x; i < n4; i += gridDim.x * blockDim.x) {
    int c = (i >> 14) & 63;
    float s = s_sc[c], h = s_sh[c];
    float4 v = t4[i], kk = k4[i], r;
    r.x = fmaf(v.x, s, h) + kk.x;
    r.y = fmaf(v.y, s, h) + kk.y;
    r.z = fmaf(v.z, s, h) + kk.z;
    r.w = fmaf(v.w, s, h) + kk.w;
    o4[i] = r;
  }
}

// ---------------------------------------------------------------------------
// Deformable conv main. R5: om (27 planes) read ONCE per pixel into registers
// (ys/xs/mk per tap); bilinear coeffs recomputed per (cb,k) from registers.
// R4 read om inside the cb loop -> 4x re-fetch of 28 MB = most of the 241 MB
// FETCH_SIZE. Offsets clamped to [-2,258] (replay-artifact insurance).
// FINAL==1 (OC==1): fuse dc4 bias + conv4 1x1, write d_out (B,1,H,W).
// ---------------------------------------------------------------------------
template <int OC, int FINAL>
__global__ __launch_bounds__(256, 2)
void dcn_kernel(const float* __restrict__ x, const float* __restrict__ om,
                const float* __restrict__ wT, const float* __restrict__ bias,
                const float* __restrict__ c4w, const float* __restrict__ c4b,
                float* __restrict__ out) {
  const int tx = threadIdx.x & 15, ty = threadIdx.x >> 4;
  const int w0 = blockIdx.x * 16, h0 = blockIdx.y * 16, b = blockIdx.z;
  const int h = h0 + ty, w = w0 + tx;
  const int p = h * 256 + w;
  float acc[OC];
#pragma unroll
  for (int o = 0; o < OC; o++) acc[o] = 0.0f;
  const float* xb  = x + (size_t)b * CHW;
  const float* omb = om + (size_t)b * 27 * HW + p;
  float ysA[9], xsA[9], mkA[9];
#pragma unroll
  for (int k = 0; k < 9; k++) {
    float dyv = omb[k * HW];
    float dxv = omb[(9 + k) * HW];
    float mo  = omb[(18 + k) * HW];
    mkA[k] = 1.0f / (1.0f + __expf(-mo));
    ysA[k] = fminf(fmaxf((float)(h + k / 3 - 1) + dyv, -2.0f), 258.0f);
    xsA[k] = fminf(fmaxf((float)(w + k % 3 - 1) + dxv, -2.0f), 258.0f);
  }
#pragma unroll 1
  for (int cb = 0; cb < 64; cb += 16) {
#pragma unroll 1
    for (int k = 0; k < 9; k++) {
      float ys = ysA[k], xs = xsA[k], mk = mkA[k];
      float y0f = floorf(ys), x0f = floorf(xs);
      float wy = ys - y0f, wx = xs - x0f;
      int y0 = (int)y0f, x0i = (int)x0f;
      int y1 = y0 + 1, x1 = x0i + 1;
      float vy0 = ((unsigned)y0  < 256u) ? 1.0f : 0.0f;
      float vy1 = ((unsigned)y1  < 256u) ? 1.0f : 0.0f;
      float vx0 = ((unsigned)x0i < 256u) ? 1.0f : 0.0f;
      float vx1 = ((unsigned)x1  < 256u) ? 1.0f : 0.0f;
      int cy0 = min(max(y0, 0), 255), cy1 = min(max(y1, 0), 255);
      int cx0 = min(max(x0i, 0), 255), cx1 = min(max(x1, 0), 255);
      int i00 = cy0 * 256 + cx0, i01 = cy0 * 256 + cx1;
      int i10 = cy1 * 256 + cx0, i11 = cy1 * 256 + cx1;
      float W00 = (1.0f - wy) * (1.0f - wx) * mk * vy0 * vx0;
      float W01 = (1.0f - wy) * wx * mk * vy0 * vx1;
      float W10 = wy * (1.0f - wx) * mk * vy1 * vx0;
      float W11 = wy * wx * mk * vy1 * vx1;
#pragma unroll 2
      for (int c = 0; c < 16; c++) {
        const float* xc = xb + (cb + c) * HW;
        float sv = W00 * xc[i00] + W01 * xc[i01] + W10 * xc[i10] + W11 * xc[i11];
        const float* wp = wT + ((cb + c) * 9 + k) * OC;   // uniform -> s_load
#pragma unroll
        for (int o = 0; o < OC; o++) acc[o] = fmaf(sv, wp[o], acc[o]);
      }
    }
  }
  if (FINAL) {
    float v = acc[0] + bias[0];
    out[(size_t)b * HW + p] = c4w[0] * v + c4b[0];
  } else {
    float* op = out + (size_t)b * OC * HW + p;
#pragma unroll
    for (int o = 0; o < OC; o++) op[o * HW] = fmaxf(acc[o] + bias[o], 0.0f);
  }
}

// ---------------------------------------------------------------------------
extern "C" void kernel_launch(void* const* d_in, const int* in_sizes, int n_in,
                              void* d_out, int out_size, void* d_ws, size_t ws_size,
                              hipStream_t stream) {
  const float* LowDEM    = (const float*)d_in[0];
  const float* Point_Ele = (const float*)d_in[1];
  const float* Slope     = (const float*)d_in[2];
  const float* Distance  = (const float*)d_in[3];
  const float* Level     = (const float*)d_in[4];
  const float* conv0_w   = (const float*)d_in[5];
  const float* conv0_b   = (const float*)d_in[6];
  const float* conv1_w   = (const float*)d_in[7];
  const float* conv1_b   = (const float*)d_in[8];
  const float* rb_w1     = (const float*)d_in[9];
  const float* rb_g1     = (const float*)d_in[11];
  const float* rb_be1    = (const float*)d_in[12];
  const float* rb_w2     = (const float*)d_in[13];
  const float* rb_g2     = (const float*)d_in[15];
  const float* rb_be2    = (const float*)d_in[16];
  const float* conv2_w   = (const float*)d_in[17];
  const float* bn2_g     = (const float*)d_in[19];
  const float* bn2_be    = (const float*)d_in[20];
  const float* dc2_w     = (const float*)d_in[21];
  const float* dc2_b     = (const float*)d_in[22];
  const float* dc2_ow    = (const float*)d_in[23];
  const float* dc2_ob    = (const float*)d_in[24];
  const float* dc3_w     = (const float*)d_in[25];
  const float* dc3_b     = (const float*)d_in[26];
  const float* dc3_ow    = (const float*)d_in[27];
  const float* dc3_ob    = (const float*)d_in[28];
  const float* dc4_w     = (const float*)d_in[29];
  const float* dc4_b     = (const float*)d_in[30];
  const float* dc4_ow    = (const float*)d_in[31];
  const float* dc4_ob    = (const float*)d_in[32];
  const float* conv4_w   = (const float*)d_in[33];
  const float* conv4_b   = (const float*)d_in[34];

  float* bufX = (float*)d_ws;             // 8388608 floats each
  float* bufY = bufX + NCHW;
  float* bufT = bufY + NCHW;
  float* bufT2= bufT + NCHW;
  float* x0   = bufT2 + NCHW;             // 131072
  float* T1   = x0 + NPIX;                // 81*64 = 5184
  float* Tdw2 = T1 + 5184;                // 36864
  float* Tdw3 = Tdw2 + 36864;             // 36864
  ushort_t* WF = (ushort_t*)(Tdw3 + 36864);   // 36 layers * 73728 ushorts
  float* stats = (float*)(WF + 36 * WFL); // 33 layers * 64 slots * 128 floats

  hipMemsetAsync(stats, 0, 33 * STSLOT * sizeof(float), stream);

  transpose_w_kernel<<<32, 256, 0, stream>>>(conv1_w, T1,   1, 64,  1, 81);
  transpose_w_kernel<<<64, 256, 0, stream>>>(dc2_w,   Tdw2, 1, 64, 64, 9);
  transpose_w_kernel<<<64, 256, 0, stream>>>(dc3_w,   Tdw3, 1, 64, 64, 9);

  prep_wfrag<<<dim3(144, 16), 256, 0, stream>>>(rb_w1,   WF,            4, 64, 36864, WFL);
  prep_wfrag<<<dim3(144, 16), 256, 0, stream>>>(rb_w2,   WF + 16 * WFL, 4, 64, 36864, WFL);
  prep_wfrag<<<dim3(144, 1),  256, 0, stream>>>(conv2_w, WF + 32 * WFL, 4, 64, 36864, WFL);
  prep_wfrag<<<dim3(72, 1),   256, 0, stream>>>(dc2_ow,  WF + 33 * WFL, 2, 27, 15552, WFL);
  prep_wfrag<<<dim3(72, 1),   256, 0, stream>>>(dc3_ow,  WF + 34 * WFL, 2, 27, 15552, WFL);
  prep_wfrag<<<dim3(72, 1),   256, 0, stream>>>(dc4_ow,  WF + 35 * WFL, 2, 27, 15552, WFL);

  prep_kernel<<<(NPIX + 255) / 256, 256, 0, stream>>>(LowDEM, Point_Ele, Slope, Distance,
                                                      Level, conv0_w, conv0_b, x0);

  dim3 grid16(16, 16, 2);   // dcn / conv9x9
  dim3 gmf(16, 64, 2);      // mfma conv3x3 (16x4 pixel tiles)

  conv9x9_kernel<<<grid16, 256, 0, stream>>>(x0, T1, conv1_b, bufX);   // X in bufX

  for (int i = 0; i < 16; i++) {
    const float* src = (i == 0) ? bufX : bufY;
    // t1 = conv(y, w1) (bias cancelled by BN); fused stats
    mfma_conv3<4, 0, 1, 64, 0><<<gmf, 256, 0, stream>>>(
        src, WF + (size_t)i * WFL, nullptr, nullptr, nullptr, nullptr,
        stats + (2 * i) * STSLOT, bufT);
    // t2 = conv(relu(bn(t1)), w2) (bn+relu fused into staging)
    mfma_conv3<4, 1, 1, 64, 0><<<gmf, 256, 0, stream>>>(
        bufT, WF + (size_t)(16 + i) * WFL, nullptr, stats + (2 * i) * STSLOT,
        rb_g1 + i * 64, rb_be1 + i * 64, stats + (2 * i + 1) * STSLOT, bufT2);
    // y = bn(t2) + y
    bn_apply_add_kernel<<<2048, 256, 0, stream>>>(bufT2, stats + (2 * i + 1) * STSLOT,
                                                  rb_g2 + i * 64, rb_be2 + i * 64, src, bufY);
  }

  // x = bn(conv2(y)) + x    -> bufX
  mfma_conv3<4, 0, 1, 64, 0><<<gmf, 256, 0, stream>>>(
      bufY, WF + (size_t)32 * WFL, nullptr, nullptr, nullptr, nullptr,
      stats + 32 * STSLOT, bufT);
  bn_apply_add_kernel<<<2048, 256, 0, stream>>>(bufT, stats + 32 * STSLOT, bn2_g, bn2_be,
                                                bufX, bufX);

  // dc2: x = relu(dcn(x)) -> bufY
  mfma_conv3<2, 0, 0, 27, 1><<<gmf, 256, 0, stream>>>(
      bufX, WF + (size_t)33 * WFL, dc2_ob, nullptr, nullptr, nullptr, nullptr, bufT);
  dcn_kernel<64, 0><<<grid16, 256, 0, stream>>>(bufX, bufT, Tdw2, dc2_b, nullptr, nullptr, bufY);

  // dc3: x = relu(dcn(x)) -> bufX
  mfma_conv3<2, 0, 0, 27, 1><<<gmf, 256, 0, stream>>>(
      bufY, WF + (size_t)34 * WFL, dc3_ob, nullptr, nullptr, nullptr, nullptr, bufT);
  dcn_kernel<64, 0><<<grid16, 256, 0, stream>>>(bufY, bufT, Tdw3, dc3_b, nullptr, nullptr, bufX);

  // dc4 + conv4 (fused) -> d_out
  mfma_conv3<2, 0, 0, 27, 1><<<gmf, 256, 0, stream>>>(
      bufX, WF + (size_t)35 * WFL, dc4_ob, nullptr, nullptr, nullptr, nullptr, bufT);
  dcn_kernel<1, 1><<<grid16, 256, 0, stream>>>(bufX, bufT, dc4_w, dc4_b, conv4_w, conv4_b,
                                               (float*)d_out);
}